// Round 10
// baseline (156.386 us; speedup 1.0000x reference)
//
#include <hip/hip_runtime.h>

// SparseMatmul3D: out[b,n,m] = sum_k x[b,n,k] * y[b,m,k]
// B=4, N=M=4096, D=64, fp32 in/out. Write-bound (268 MB out, floor ~38us @7TB/s).
// R1: 128x128 tiles, direct stores               -> 89.7 us (~3.0 TB/s)
// R2: 128x128, LDS full-line stores (+NT)        -> 94.5 us
// R3/R5: slabs (+stagger)                        -> 163/132 us
// R7: 16x512 tiles, LDS 1KB runs                 -> 143 us
// R8: 64x64 per-wave tiles, stores-at-end        -> 91.2 us
// R9: R8 + nontemporal                           -> 89.5 us (NT neutral)
//   All pinned at ~3 TB/s. Last untested lever: WRITE-FRONT DENSITY. R8's
//   per-block burst covers 6% of a 1MB range; channel-hashed DRAM wants
//   dense contiguous windows for page locality.
// R10: block = 16 consecutive rows x FULL 4096 m = 256KB contiguous, 100%
//   covered in one end-of-block burst. 1024-thread blocks, 16 waves, each a
//   256-wide m-quarter; no LDS/barriers; stores only at end (R8 properties).

#define BATCH 4
#define NN 4096
#define MM 4096
#define DD 64

typedef __attribute__((ext_vector_type(8))) short bf16x8;
typedef __attribute__((ext_vector_type(4))) float f32x4;

__device__ __forceinline__ unsigned short f2bf(float f) {
    unsigned u = __builtin_bit_cast(unsigned, f);
    u += 0x7FFFu + ((u >> 16) & 1u);   // round-to-nearest-even
    return (unsigned short)(u >> 16);
}

__device__ __forceinline__ bf16x8 load8_bf16(const float* __restrict__ p) {
    f32x4 v0 = *reinterpret_cast<const f32x4*>(p);
    f32x4 v1 = *reinterpret_cast<const f32x4*>(p + 4);
    bf16x8 r;
    r[0] = (short)f2bf(v0[0]); r[1] = (short)f2bf(v0[1]);
    r[2] = (short)f2bf(v0[2]); r[3] = (short)f2bf(v0[3]);
    r[4] = (short)f2bf(v1[0]); r[5] = (short)f2bf(v1[1]);
    r[6] = (short)f2bf(v1[2]); r[7] = (short)f2bf(v1[3]);
    return r;
}

__global__ __launch_bounds__(1024, 4) void
SparseMatmul3D_36155034698289_kernel(const float* __restrict__ x,
                                     const float* __restrict__ y,
                                     float* __restrict__ out) {
    const int bid  = blockIdx.x;                    // [0,1024)
    const int b    = (bid & 7) >> 1;                // 2 XCDs per batch
    const int band = ((bid >> 3) << 1) | (bid & 1); // [0,256)
    const int n0   = band * 16;

    const int w    = threadIdx.x >> 6;   // 16 waves: m-quarter [0,16)
    const int lane = threadIdx.x & 63;
    const int m0   = w * 256;

    const int row16 = lane & 15;
    const int kgrp  = lane >> 4;

    const float* __restrict__ xb = x + (size_t)b * NN * DD;
    const float* __restrict__ yb = y + (size_t)b * MM * DD;

    // B operand = x rows (n side): this block's single 16-row subtile
    bf16x8 bfrag[2];
    {
        const float* p = xb + (size_t)(n0 + row16) * DD + kgrp * 8;
        bfrag[0] = load8_bf16(p);
        bfrag[1] = load8_bf16(p + 32);
    }

    f32x4 acc[16];                        // 16n x 256m per wave = 64 VGPR
#pragma unroll
    for (int mt = 0; mt < 16; ++mt) acc[mt] = (f32x4){0.f, 0.f, 0.f, 0.f};

    const float* __restrict__ ybase = yb + (size_t)(m0 + row16) * DD + kgrp * 8;

#pragma unroll
    for (int mt = 0; mt < 16; ++mt) {
        bf16x8 a0 = load8_bf16(ybase + (size_t)mt * 16 * DD);
        bf16x8 a1 = load8_bf16(ybase + (size_t)mt * 16 * DD + 32);
        acc[mt] = __builtin_amdgcn_mfma_f32_16x16x32_bf16(a0, bfrag[0], acc[mt], 0, 0, 0);
        acc[mt] = __builtin_amdgcn_mfma_f32_16x16x32_bf16(a1, bfrag[1], acc[mt], 0, 0, 0);
    }

    // End-of-block burst: 16 waves together cover n0..n0+16 x m 0..4096 =
    // 256 KB contiguous output range, 100% dense.
    // D layout: col = lane&15 = n; row = kgrp*4+reg = m (4 consecutive m).
    float* __restrict__ orow = out + (size_t)b * NN * MM
                             + (size_t)(n0 + row16) * MM + m0 + kgrp * 4;
#pragma unroll
    for (int mt = 0; mt < 16; ++mt)
        *reinterpret_cast<f32x4*>(orow + mt * 16) = acc[mt];
}

extern "C" void kernel_launch(void* const* d_in, const int* in_sizes, int n_in,
                              void* d_out, int out_size, void* d_ws, size_t ws_size,
                              hipStream_t stream) {
    const float* x = (const float*)d_in[0];
    const float* y = (const float*)d_in[1];
    float* out = (float*)d_out;

    dim3 grid(1024);
    dim3 block(1024);
    SparseMatmul3D_36155034698289_kernel<<<grid, block, 0, stream>>>(x, y, out);
}

// Round 11
// 92.380 us; speedup vs baseline: 1.6928x; 1.6928x over previous
//
#include <hip/hip_runtime.h>

// SparseMatmul3D: out[b,n,m] = sum_k x[b,n,k] * y[b,m,k]
// B=4, N=M=4096, D=64, fp32 in/out. Write-bound (268 MB out, floor ~38us @7TB/s).
// R1: 128x128 tiles, direct stores               -> 89.7 us (~3.0 TB/s)
// R2: 128x128, LDS full-line stores (+NT)        -> 94.5 us
// R3/R5: 16-32-row slabs (+stagger)              -> 163/132 us
// R7: 16x512 tiles, LDS 1KB runs                 -> 143 us
// R8: 64x256 block (4 waves of 64x64 in m-row)   -> 91.2 us
// R9: R8 + nontemporal                           -> 89.5 us (NT neutral)
// R10: 16x4096 dense 256KB burst                 -> 156 us (density INVERTED)
//   Empirical law: >=64 n-rows per block -> ~90us; 16-32 rows -> 130-165us.
//   All micro-mechanisms (segmentation, NT, stagger, density, duty) falsified.
// R11: aspect-gradient probe: 256n x 64m block = R8's exact per-wave 64x64 unit,
//   4 waves stacked VERTICALLY. Single variable vs R8: block aspect.

#define BATCH 4
#define NN 4096
#define MM 4096
#define DD 64

typedef __attribute__((ext_vector_type(8))) short bf16x8;
typedef __attribute__((ext_vector_type(4))) float f32x4;

__device__ __forceinline__ unsigned short f2bf(float f) {
    unsigned u = __builtin_bit_cast(unsigned, f);
    u += 0x7FFFu + ((u >> 16) & 1u);   // round-to-nearest-even
    return (unsigned short)(u >> 16);
}

__device__ __forceinline__ bf16x8 load8_bf16(const float* __restrict__ p) {
    f32x4 v0 = *reinterpret_cast<const f32x4*>(p);
    f32x4 v1 = *reinterpret_cast<const f32x4*>(p + 4);
    bf16x8 r;
    r[0] = (short)f2bf(v0[0]); r[1] = (short)f2bf(v0[1]);
    r[2] = (short)f2bf(v0[2]); r[3] = (short)f2bf(v0[3]);
    r[4] = (short)f2bf(v1[0]); r[5] = (short)f2bf(v1[1]);
    r[6] = (short)f2bf(v1[2]); r[7] = (short)f2bf(v1[3]);
    return r;
}

__global__ __launch_bounds__(256, 4) void
SparseMatmul3D_36155034698289_kernel(const float* __restrict__ x,
                                     const float* __restrict__ y,
                                     float* __restrict__ out) {
    const int bid = blockIdx.x;            // [0,4096)
    const int mc  = bid & 63;              // m-tile (fastest)
    const int nt4 = (bid >> 6) & 15;       // n-supertile [0,16)
    const int b   = bid >> 10;             // batch

    const int w    = threadIdx.x >> 6;     // 4 waves stacked in n
    const int lane = threadIdx.x & 63;
    const int n0   = nt4 * 256 + w * 64;   // this wave's 64-row n-band
    const int m0   = mc * 64;              // shared 64-wide m-window

    const int row16 = lane & 15;
    const int kgrp  = lane >> 4;

    const float* __restrict__ xb = x + (size_t)b * NN * DD;
    const float* __restrict__ yb = y + (size_t)b * MM * DD;

    // B operand = x rows (n side): 4 n-subtiles
    bf16x8 bfrag[4][2];
#pragma unroll
    for (int j = 0; j < 4; ++j) {
        const float* p = xb + (size_t)(n0 + j * 16 + row16) * DD + kgrp * 8;
        bfrag[j][0] = load8_bf16(p);
        bfrag[j][1] = load8_bf16(p + 32);
    }

    f32x4 acc[4][4];
#pragma unroll
    for (int i = 0; i < 4; ++i)
#pragma unroll
        for (int j = 0; j < 4; ++j)
            acc[i][j] = (f32x4){0.f, 0.f, 0.f, 0.f};

    // A operand = y rows (m side): 4 m-subtiles, loaded in 2 halves (VGPR cap)
#pragma unroll
    for (int h = 0; h < 2; ++h) {
        bf16x8 af[2][2];
#pragma unroll
        for (int i = 0; i < 2; ++i) {
            const float* p = yb + (size_t)(m0 + (h * 2 + i) * 16 + row16) * DD + kgrp * 8;
            af[i][0] = load8_bf16(p);
            af[i][1] = load8_bf16(p + 32);
        }
#pragma unroll
        for (int ks = 0; ks < 2; ++ks)
#pragma unroll
            for (int i = 0; i < 2; ++i)
#pragma unroll
                for (int j = 0; j < 4; ++j)
                    acc[h * 2 + i][j] = __builtin_amdgcn_mfma_f32_16x16x32_bf16(
                        af[i][ks], bfrag[j][ks], acc[h * 2 + i][j], 0, 0, 0);
    }

    // Stores only at kernel end (no vmcnt serialization).
    // D layout: col = lane&15 = n; row = kgrp*4+reg = m (4 consecutive m).
    float* __restrict__ ob = out + (size_t)b * NN * MM;
#pragma unroll
    for (int j = 0; j < 4; ++j) {
        const int n = n0 + j * 16 + row16;
        float* orow = ob + (size_t)n * MM;
#pragma unroll
        for (int i = 0; i < 4; ++i)
            *reinterpret_cast<f32x4*>(orow + m0 + i * 16 + kgrp * 4) = acc[i][j];
    }
}

extern "C" void kernel_launch(void* const* d_in, const int* in_sizes, int n_in,
                              void* d_out, int out_size, void* d_ws, size_t ws_size,
                              hipStream_t stream) {
    const float* x = (const float*)d_in[0];
    const float* y = (const float*)d_in[1];
    float* out = (float*)d_out;

    dim3 grid(4096);
    dim3 block(256);
    SparseMatmul3D_36155034698289_kernel<<<grid, block, 0, stream>>>(x, y, out);
}